// Round 16
// baseline (74.800 us; speedup 1.0000x reference)
//
#include <hip/hip_runtime.h>
#include <cmath>

// JPEG layer, fully fused. One wave handles 4 horizontal 16x16 tiles.
// R15 vs R6 champion: the two Y codec rounds (independent blocks A,B) are
// PACKED into one float2 codec -> v_pk_fma_f32 halves FMA issue count and
// doubles ILP on the serial DCT chains. Chroma codec packs (Cb,Cr) of each
// tile (groups 0-3 useful, 4-7 duplicate/discarded). NT stores reverted
// (R14: +25% write bytes, no time change).

#define LEVELD 0.5019607843137255
#define LEVELF 0.5019607843137255f
#define BAND   5.0e-5f

#define CA  0.35355339059327373f
#define CB0 0.49039264020161522f
#define CB1 0.41573480615127262f
#define CB2 0.27778511650980114f
#define CB3 0.09754516100806413f
#define CC0 0.46193976625564337f
#define CC1 0.19134171618254489f

typedef float f2 __attribute__((ext_vector_type(2)));

__device__ __forceinline__ f2 pkfma(f2 a, f2 b, f2 c) { return a * b + c; }  // contracts to v_pk_fma_f32
__device__ __forceinline__ f2 pkfma(float a, f2 b, f2 c) { f2 av = {a, a}; return av * b + c; }

__device__ const double DMATD[64] = {
  0.3535533905932738,  0.3535533905932738,  0.3535533905932738,  0.3535533905932738,
  0.3535533905932738,  0.3535533905932738,  0.3535533905932738,  0.3535533905932738,
  0.4903926402016152,  0.4157348061512726,  0.2777851165098011,  0.0975451610080641,
 -0.0975451610080641, -0.2777851165098011, -0.4157348061512726, -0.4903926402016152,
  0.4619397662556434,  0.1913417161825449, -0.1913417161825449, -0.4619397662556434,
 -0.4619397662556434, -0.1913417161825449,  0.1913417161825449,  0.4619397662556434,
  0.4157348061512726, -0.0975451610080641, -0.4903926402016152, -0.2777851165098011,
  0.2777851165098011,  0.4903926402016152,  0.0975451610080641, -0.4157348061512726,
  0.3535533905932738, -0.3535533905932738, -0.3535533905932738,  0.3535533905932738,
  0.3535533905932738, -0.3535533905932738, -0.3535533905932738,  0.3535533905932738,
  0.2777851165098011, -0.4903926402016152,  0.0975451610080641,  0.4157348061512726,
 -0.4157348061512726, -0.0975451610080641,  0.4903926402016152, -0.2777851165098011,
  0.1913417161825449, -0.4619397662556434,  0.4619397662556434, -0.1913417161825449,
 -0.1913417161825449,  0.4619397662556434, -0.4619397662556434,  0.1913417161825449,
  0.0975451610080641, -0.2777851165098011,  0.4157348061512726, -0.4903926402016152,
  0.4903926402016152, -0.4157348061512726,  0.2777851165098011, -0.0975451610080641
};

// ---- DPP cross-lane helpers (VALU only) ----
__device__ __forceinline__ float dpp_xor1(float x) {  // quad_perm(1,0,3,2)
  return __int_as_float(__builtin_amdgcn_mov_dpp(__float_as_int(x), 0xB1, 0xF, 0xF, true));
}
__device__ __forceinline__ float dpp_xor2(float x) {  // quad_perm(2,3,0,1)
  return __int_as_float(__builtin_amdgcn_mov_dpp(__float_as_int(x), 0x4E, 0xF, 0xF, true));
}
__device__ __forceinline__ float dpp_xor4(float x) {  // half_mirror o quad_mirror
  int t = __builtin_amdgcn_mov_dpp(__float_as_int(x), 0x141, 0xF, 0xF, true);
  return __int_as_float(__builtin_amdgcn_mov_dpp(t, 0x1B, 0xF, 0xF, true));
}
__device__ __forceinline__ f2 dpp_xor1v(f2 x) { f2 r; r.x = dpp_xor1(x.x); r.y = dpp_xor1(x.y); return r; }
__device__ __forceinline__ f2 dpp_xor2v(f2 x) { f2 r; r.x = dpp_xor2(x.x); r.y = dpp_xor2(x.y); return r; }
__device__ __forceinline__ f2 dpp_xor4v(f2 x) { f2 r; r.x = dpp_xor4(x.x); r.y = dpp_xor4(x.y); return r; }

// packed in-register 8x8 transpose across the 8 lanes of a group
__device__ __forceinline__ void transpose8p(f2 v[8], int p) {
  { f2 t[8];
    #pragma unroll
    for (int j = 0; j < 8; ++j) t[j] = dpp_xor1v(v[j ^ 1]);
    const bool lb = (p & 1) != 0;
    #pragma unroll
    for (int j = 0; j < 8; ++j) v[j] = (lb == ((j & 1) != 0)) ? v[j] : t[j];
  }
  { f2 t[8];
    #pragma unroll
    for (int j = 0; j < 8; ++j) t[j] = dpp_xor2v(v[j ^ 2]);
    const bool lb = (p & 2) != 0;
    #pragma unroll
    for (int j = 0; j < 8; ++j) v[j] = (lb == ((j & 2) != 0)) ? v[j] : t[j];
  }
  { f2 t[8];
    #pragma unroll
    for (int j = 0; j < 8; ++j) t[j] = dpp_xor4v(v[j ^ 4]);
    const bool lb = (p & 4) != 0;
    #pragma unroll
    for (int j = 0; j < 8; ++j) v[j] = (lb == ((j & 4) != 0)) ? v[j] : t[j];
  }
}

// packed forward 8-pt DCT (y = D x), butterflied
__device__ __forceinline__ void fdct8p(f2 x[8]) {
  const f2 s0 = x[0] + x[7], s1 = x[1] + x[6], s2 = x[2] + x[5], s3 = x[3] + x[4];
  const f2 d0 = x[0] - x[7], d1 = x[1] - x[6], d2 = x[2] - x[5], d3 = x[3] - x[4];
  const f2 t0 = s0 + s3, t1 = s1 + s2, t2 = s0 - s3, t3 = s1 - s2;
  x[0] = CA * (t0 + t1);
  x[4] = CA * (t0 - t1);
  x[2] = pkfma(CC0, t2,  CC1 * t3);
  x[6] = pkfma(CC1, t2, -CC0 * t3);
  x[1] = pkfma(CB0, d0, pkfma( CB1, d1, pkfma( CB2, d2,  CB3 * d3)));
  x[3] = pkfma(CB1, d0, pkfma(-CB3, d1, pkfma(-CB0, d2, -CB2 * d3)));
  x[5] = pkfma(CB2, d0, pkfma(-CB0, d1, pkfma( CB3, d2,  CB1 * d3)));
  x[7] = pkfma(CB3, d0, pkfma(-CB2, d1, pkfma( CB1, d2, -CB0 * d3)));
}
// packed inverse 8-pt DCT (o = D^T y), butterflied
__device__ __forceinline__ void idct8p(f2 y[8]) {
  const f2 pe = CA * (y[0] + y[4]), qe = CA * (y[0] - y[4]);
  const f2 re = pkfma(CC0, y[2],  CC1 * y[6]);
  const f2 se = pkfma(CC1, y[2], -CC0 * y[6]);
  const f2 E0 = pe + re, E3 = pe - re, E1 = qe + se, E2 = qe - se;
  const f2 O0 = pkfma(CB0, y[1], pkfma( CB1, y[3], pkfma( CB2, y[5],  CB3 * y[7])));
  const f2 O1 = pkfma(CB1, y[1], pkfma(-CB3, y[3], pkfma(-CB0, y[5], -CB2 * y[7])));
  const f2 O2 = pkfma(CB2, y[1], pkfma(-CB0, y[3], pkfma( CB3, y[5],  CB1 * y[7])));
  const f2 O3 = pkfma(CB3, y[1], pkfma(-CB2, y[3], pkfma( CB1, y[5], -CB0 * y[7])));
  y[0] = E0 + O0; y[7] = E0 - O0;
  y[1] = E1 + O1; y[6] = E1 - O1;
  y[2] = E2 + O2; y[5] = E2 - O2;
  y[3] = E3 + O3; y[4] = E3 - O3;
}

// f64 recompute of dequantized coefficient (i,j). mode 0 = Y (base = 8x8
// block base), mode 1 = Cb, mode 2 = Cr (base = 16x16 tile base). Cold.
__device__ __attribute__((noinline)) float rescue_coef(
    const float* __restrict__ quant, const float* __restrict__ base,
    int mode, int i, int j)
{
  double acc = 0.0;
  if (mode == 0) {
    #pragma unroll 1
    for (int k = 0; k < 8; ++k) {
      double e = 0.0;
      #pragma unroll
      for (int l = 0; l < 8; ++l) {
        const size_t off = (size_t)k * 512 + l;
        const double rr = (double)base[off];
        const double gg = (double)base[262144 + off];
        const double bb = (double)base[524288 + off];
        double y = 0.299 * rr + 0.587 * gg + 0.114 * bb;
        y = fmin(fmax(y, 0.0), 1.0) - LEVELD;
        e += y * DMATD[j * 8 + l];
      }
      acc += DMATD[i * 8 + k] * e;
    }
  } else {
    const double c0 = (mode == 1) ? -0.168735892 : 0.5;
    const double c1 = (mode == 1) ? -0.331264108 : -0.418687589;
    const double c2 = (mode == 1) ?  0.5         : -0.081312411;
    #pragma unroll 1
    for (int k = 0; k < 8; ++k) {
      double e = 0.0;
      #pragma unroll 1
      for (int l = 0; l < 8; ++l) {
        double m = 0.0;
        #pragma unroll
        for (int dr = 0; dr < 2; ++dr)
          #pragma unroll
          for (int dc = 0; dc < 2; ++dc) {
            const size_t off = (size_t)(2 * k + dr) * 512 + (2 * l + dc);
            const double rr = (double)base[off];
            const double gg = (double)base[262144 + off];
            const double bb = (double)base[524288 + off];
            const double v = c0 * rr + c1 * gg + c2 * bb;
            m += fmin(fmax(v + LEVELD, 0.0), 1.0) - LEVELD;
          }
        e += (0.25 * m) * DMATD[j * 8 + l];
      }
      acc += DMATD[i * 8 + k] * e;
    }
  }
  const double qd = rint((double)quant[i * 8 + j] * 255.0) * (1.0 / 255.0);
  return (float)(rint(acc / qd) * qd);
}

// packed per-block-pair codec: DCT -> quant(round; deferred f64 rescue per
// component) -> IDCT, in place. Component .x: (baseX,modeX); .y: (baseY,modeY).
__device__ __forceinline__ void codec8p(
    f2 x[8], const float qv[8], const float rq[8], int p, bool doRescue,
    const float* __restrict__ baseX, int modeX,
    const float* __restrict__ baseY, int modeY,
    const float* __restrict__ quant)
{
  fdct8p(x); transpose8p(x, p); fdct8p(x);
  unsigned badX = 0u, badY = 0u;
  #pragma unroll
  for (int i = 0; i < 8; ++i) {
    const f2 tt = x[i] * rq[i];
    const float rtx = rintf(tt.x);
    const float rty = rintf(tt.y);
    if (fabsf(tt.x - rtx) > 0.5f - BAND) badX |= (1u << i);
    if (fabsf(tt.y - rty) > 0.5f - BAND) badY |= (1u << i);
    f2 rt = {rtx, rty};
    x[i] = rt * qv[i];
  }
  if (!doRescue) { badX = 0u; badY = 0u; }
  if (__builtin_expect(badX != 0u, 0)) {
    do {
      const int i = __builtin_ctz(badX);
      badX &= badX - 1u;
      const float fix = rescue_coef(quant, baseX, modeX, i, p);
      #pragma unroll
      for (int k = 0; k < 8; ++k) if (k == i) x[k].x = fix;
    } while (badX != 0u);
  }
  if (__builtin_expect(badY != 0u, 0)) {
    do {
      const int i = __builtin_ctz(badY);
      badY &= badY - 1u;
      const float fix = rescue_coef(quant, baseY, modeY, i, p);
      #pragma unroll
      for (int k = 0; k < 8; ++k) if (k == i) x[k].y = fix;
    } while (badY != 0u);
  }
  idct8p(x); transpose8p(x, p); idct8p(x);
}

// color + chroma-mean staging for one Y round (loads already in registers)
__device__ __forceinline__ void color_stage(
    const float4 L6[6], int tY, int qr, int qc, int p,
    float4* __restrict__ CHW, float rout[8])
{
  const float RL[8] = {L6[0].x, L6[0].y, L6[0].z, L6[0].w, L6[1].x, L6[1].y, L6[1].z, L6[1].w};
  const float GL[8] = {L6[2].x, L6[2].y, L6[2].z, L6[2].w, L6[3].x, L6[3].y, L6[3].z, L6[3].w};
  const float BL[8] = {L6[4].x, L6[4].y, L6[4].z, L6[4].w, L6[5].x, L6[5].y, L6[5].z, L6[5].w};

  float cbv[8], crv[8];
  #pragma unroll
  for (int l = 0; l < 8; ++l) {
    const float rr = RL[l], gg = GL[l], bb = BL[l];
    const float y  = fmaf(0.114f, bb, fmaf(0.587f, gg, 0.299f * rr));
    const float cb = fmaf(0.5f, bb, fmaf(-0.331264108f, gg, -0.168735892f * rr));
    const float cr = fmaf(-0.081312411f, bb, fmaf(-0.418687589f, gg, 0.5f * rr));
    rout[l] = fminf(fmaxf(y,           0.0f), 1.0f) - LEVELF;
    cbv[l]  = fminf(fmaxf(cb + LEVELF, 0.0f), 1.0f) - LEVELF;
    crv[l]  = fminf(fmaxf(cr + LEVELF, 0.0f), 1.0f) - LEVELF;
  }
  float ch[4];
  #pragma unroll
  for (int j = 0; j < 4; ++j) {
    const float cbh = cbv[2 * j] + cbv[2 * j + 1];
    const float crh = crv[2 * j] + crv[2 * j + 1];
    const float cbs = cbh + dpp_xor1(cbh);
    const float crs = crh + dpp_xor1(crh);
    ch[j] = 0.25f * ((p & 1) ? crs : cbs);   // even lanes: cb, odd: cr
  }
  const int crow = qr * 4 + (p >> 1);
  const int slot = ((((p & 1) * 4 + tY) * 16) + crow * 2 + qc) ^ ((tY << 1) | qr);
  CHW[slot] = make_float4(ch[0], ch[1], ch[2], ch[3]);
}

// upsample chroma from LDS, YCC->RGB, clamp, store one Y round
__device__ __forceinline__ void out_phase(
    float* __restrict__ ob, int tY, int qr, int qc, int p,
    const float4* __restrict__ CHW, const float r[8])
{
  const int crow = qr * 4 + (p >> 1);
  const int swz = (tY << 1) | qr;
  const float4 cb4 = CHW[((tY * 16) + crow * 2 + qc) ^ swz];
  const float4 cr4 = CHW[(((4 + tY) * 16) + crow * 2 + qc) ^ swz];
  const float cba[4] = {cb4.x, cb4.y, cb4.z, cb4.w};
  const float cra[4] = {cr4.x, cr4.y, cr4.z, cr4.w};

  float RR[8], GG[8], BB[8];
  #pragma unroll
  for (int l = 0; l < 8; ++l) {
    const float y2 = r[l] + LEVELF;          // chroma LEVEL offsets cancel
    const float cbb = cba[l >> 1], crr = cra[l >> 1];
    float ro = fmaf(1.402f, crr, y2);
    float go = y2 - 0.344136286f * cbb - 0.714136286f * crr;
    float bo = fmaf(1.772f, cbb, y2);
    RR[l] = fminf(fmaxf(ro, 0.0f), 1.0f);
    GG[l] = fminf(fmaxf(go, 0.0f), 1.0f);
    BB[l] = fminf(fmaxf(bo, 0.0f), 1.0f);
  }
  float* op = ob + (size_t)(qr * 8 + p) * 512 + tY * 16 + qc * 8;
  *(float4*)(op)              = make_float4(RR[0], RR[1], RR[2], RR[3]);
  *(float4*)(op + 4)          = make_float4(RR[4], RR[5], RR[6], RR[7]);
  *(float4*)(op + 262144)     = make_float4(GG[0], GG[1], GG[2], GG[3]);
  *(float4*)(op + 262148)     = make_float4(GG[4], GG[5], GG[6], GG[7]);
  *(float4*)(op + 524288)     = make_float4(BB[0], BB[1], BB[2], BB[3]);
  *(float4*)(op + 524292)     = make_float4(BB[4], BB[5], BB[6], BB[7]);
}

__global__ __launch_bounds__(64, 4) void jpeg_fused(
    const float* __restrict__ in, const float* __restrict__ quant,
    float* __restrict__ out)
{
  __shared__ float4 CH[128];   // 8 chroma blocks (swizzled slots), 2 KiB

  const int lane = threadIdx.x;
  const int g = lane >> 3, p = lane & 7;
  const int tx = g >> 2, qr = (g >> 1) & 1, qc = g & 1;

  const int u    = blockIdx.x;                // unit = 4 tiles in a row
  const int img  = u >> 8;
  const int trow = (u >> 3) & 31;
  const int tcq  = u & 7;
  const size_t tboff = (size_t)img * 786432 + (size_t)trow * 16 * 512 + (size_t)tcq * 64;
  const float* tb = in + tboff;
  float* ob = out + tboff;

  // ---- hoisted global loads: both Y rounds' pixels + quant column ----
  float4 L[2][6];
  #pragma unroll
  for (int h = 0; h < 2; ++h) {
    const int tY = 2 * h + tx;
    const float* pb = tb + (size_t)(qr * 8 + p) * 512 + tY * 16 + qc * 8;
    L[h][0] = *(const float4*)(pb);
    L[h][1] = *(const float4*)(pb + 4);
    L[h][2] = *(const float4*)(pb + 262144);
    L[h][3] = *(const float4*)(pb + 262148);
    L[h][4] = *(const float4*)(pb + 524288);
    L[h][5] = *(const float4*)(pb + 524292);
  }
  float qf[8];
  #pragma unroll
  for (int i = 0; i < 8; ++i) qf[i] = quant[i * 8 + p];

  // quantizer column p in f32: rintf(q*255) is exact (q*255 in [40,50]);
  // <=1-ulp dequant difference vs f64, arbitrated by the f64 rescue anyway
  float qv[8], rq[8];
  #pragma unroll
  for (int i = 0; i < 8; ++i) {
    qv[i] = rintf(qf[i] * 255.0f) * (1.0f / 255.0f);
    rq[i] = 1.0f / qv[i];
  }

  // ---- color + chroma staging for both rounds ----
  float rA[8], rB[8];
  color_stage(L[0], 2 * 0 + tx, qr, qc, p, CH, rA);
  color_stage(L[1], 2 * 1 + tx, qr, qc, p, CH, rB);
  __builtin_amdgcn_wave_barrier();

  // ---- PACKED Y codec: components (.x = round A, .y = round B) ----
  {
    f2 x[8];
    #pragma unroll
    for (int i = 0; i < 8; ++i) { x[i].x = rA[i]; x[i].y = rB[i]; }
    const float* blkA = tb + (size_t)(qr * 8) * 512 + (2 * 0 + tx) * 16 + qc * 8;
    const float* blkB = tb + (size_t)(qr * 8) * 512 + (2 * 1 + tx) * 16 + qc * 8;
    codec8p(x, qv, rq, p, true, blkA, 0, blkB, 0, quant);
    #pragma unroll
    for (int i = 0; i < 8; ++i) { rA[i] = x[i].x; rB[i] = x[i].y; }
  }

  // ---- PACKED chroma codec: tile ct = g&3, components (.x=Cb, .y=Cr).
  //      Groups 0-3 are authoritative; groups 4-7 compute duplicates that
  //      are never written back (and never rescue). ----
  {
    const int ct = g & 3;
    const int preB = (0 * 4 + ct) * 16 + p * 2;     // Cb slots
    const int preR = (1 * 4 + ct) * 16 + p * 2;     // Cr slots
    const int swz  = (ct << 1) | (p >> 2);
    const int slB = preB ^ swz, shB = (preB + 1) ^ swz;
    const int slR = preR ^ swz, shR = (preR + 1) ^ swz;
    const float4 ab = CH[slB];
    const float4 bb = CH[shB];
    const float4 ar = CH[slR];
    const float4 br = CH[shR];
    f2 x[8];
    x[0].x = ab.x; x[1].x = ab.y; x[2].x = ab.z; x[3].x = ab.w;
    x[4].x = bb.x; x[5].x = bb.y; x[6].x = bb.z; x[7].x = bb.w;
    x[0].y = ar.x; x[1].y = ar.y; x[2].y = ar.z; x[3].y = ar.w;
    x[4].y = br.x; x[5].y = br.y; x[6].y = br.z; x[7].y = br.w;

    codec8p(x, qv, rq, p, g < 4, tb + ct * 16, 1, tb + ct * 16, 2, quant);

    __builtin_amdgcn_wave_barrier();
    if (g < 4) {
      CH[slB] = make_float4(x[0].x, x[1].x, x[2].x, x[3].x);
      CH[shB] = make_float4(x[4].x, x[5].x, x[6].x, x[7].x);
      CH[slR] = make_float4(x[0].y, x[1].y, x[2].y, x[3].y);
      CH[shR] = make_float4(x[4].y, x[5].y, x[6].y, x[7].y);
    }
  }
  __builtin_amdgcn_wave_barrier();

  // ---- output both rounds ----
  out_phase(ob, 2 * 0 + tx, qr, qc, p, CH, rA);
  out_phase(ob, 2 * 1 + tx, qr, qc, p, CH, rB);
}

extern "C" void kernel_launch(void* const* d_in, const int* in_sizes, int n_in,
                              void* d_out, int out_size, void* d_ws, size_t ws_size,
                              hipStream_t stream) {
  const float* in    = (const float*)d_in[0];
  const float* quant = (const float*)d_in[1];  // only quantize[0] (64 floats) used
  float* out = (float*)d_out;

  // 8192 single-wave workgroups (32 img x 32 trow x 8 four-tile units)
  jpeg_fused<<<dim3(8192), dim3(64), 0, stream>>>(in, quant, out);
}

// Round 17
// 63.504 us; speedup vs baseline: 1.1779x; 1.1779x over previous
//
#include <hip/hip_runtime.h>
#include <cmath>

// JPEG layer, fully fused — CHAMPION (R14, 63.25 us measured).
// One wave (= one 64-thread workgroup) handles 4 horizontally-consecutive
// 16x16 tiles: 16 Y blocks + 4 Cb + 4 Cr = 24 blocks in 3 full-lane rounds.
// Lane (g = lane>>3, p = lane&7) owns row p of block-slot g. Butterfly 8-pt
// DCT/IDCT in-lane + DPP in-register 8x8 transposes. All global loads
// hoisted to the kernel top; quantizer fast path is call-free with a
// deferred f64 rescue patch; non-temporal output stores.
// Session plateau: 4 independent designs land 63-73 us; 7 single-variable
// probes on this structure all neutral/negative. Floor arithmetic:
// ~31 us memory + ~21 us VALU at ~50% overlap efficiency -> ~63 us.

#define LEVELD 0.5019607843137255
#define LEVELF 0.5019607843137255f
#define BAND   5.0e-5f

#define CA  0.35355339059327373f
#define CB0 0.49039264020161522f
#define CB1 0.41573480615127262f
#define CB2 0.27778511650980114f
#define CB3 0.09754516100806413f
#define CC0 0.46193976625564337f
#define CC1 0.19134171618254489f

typedef float v4f __attribute__((ext_vector_type(4)));

__device__ __forceinline__ void nt_store4(float* p, float a, float b, float c, float d) {
  v4f v = {a, b, c, d};
  __builtin_nontemporal_store(v, (v4f*)p);
}

__device__ const double DMATD[64] = {
  0.3535533905932738,  0.3535533905932738,  0.3535533905932738,  0.3535533905932738,
  0.3535533905932738,  0.3535533905932738,  0.3535533905932738,  0.3535533905932738,
  0.4903926402016152,  0.4157348061512726,  0.2777851165098011,  0.0975451610080641,
 -0.0975451610080641, -0.2777851165098011, -0.4157348061512726, -0.4903926402016152,
  0.4619397662556434,  0.1913417161825449, -0.1913417161825449, -0.4619397662556434,
 -0.4619397662556434, -0.1913417161825449,  0.1913417161825449,  0.4619397662556434,
  0.4157348061512726, -0.0975451610080641, -0.4903926402016152, -0.2777851165098011,
  0.2777851165098011,  0.4903926402016152,  0.0975451610080641, -0.4157348061512726,
  0.3535533905932738, -0.3535533905932738, -0.3535533905932738,  0.3535533905932738,
  0.3535533905932738, -0.3535533905932738, -0.3535533905932738,  0.3535533905932738,
  0.2777851165098011, -0.4903926402016152,  0.0975451610080641,  0.4157348061512726,
 -0.4157348061512726, -0.0975451610080641,  0.4903926402016152, -0.2777851165098011,
  0.1913417161825449, -0.4619397662556434,  0.4619397662556434, -0.1913417161825449,
 -0.1913417161825449,  0.4619397662556434, -0.4619397662556434,  0.1913417161825449,
  0.0975451610080641, -0.2777851165098011,  0.4157348061512726, -0.4903926402016152,
  0.4903926402016152, -0.4157348061512726,  0.2777851165098011, -0.0975451610080641
};

// ---- DPP cross-lane helpers (VALU only) ----
__device__ __forceinline__ float dpp_xor1(float x) {  // quad_perm(1,0,3,2)
  return __int_as_float(__builtin_amdgcn_mov_dpp(__float_as_int(x), 0xB1, 0xF, 0xF, true));
}
__device__ __forceinline__ float dpp_xor2(float x) {  // quad_perm(2,3,0,1)
  return __int_as_float(__builtin_amdgcn_mov_dpp(__float_as_int(x), 0x4E, 0xF, 0xF, true));
}
__device__ __forceinline__ float dpp_xor4(float x) {  // half_mirror o quad_mirror
  int t = __builtin_amdgcn_mov_dpp(__float_as_int(x), 0x141, 0xF, 0xF, true);
  return __int_as_float(__builtin_amdgcn_mov_dpp(t, 0x1B, 0xF, 0xF, true));
}

// in-register 8x8 transpose across the 8 lanes of a group; v[j]@p -> v[p]@j
__device__ __forceinline__ void transpose8(float v[8], int p) {
  { float t[8];
    #pragma unroll
    for (int j = 0; j < 8; ++j) t[j] = dpp_xor1(v[j ^ 1]);
    const bool lb = (p & 1) != 0;
    #pragma unroll
    for (int j = 0; j < 8; ++j) v[j] = (lb == ((j & 1) != 0)) ? v[j] : t[j];
  }
  { float t[8];
    #pragma unroll
    for (int j = 0; j < 8; ++j) t[j] = dpp_xor2(v[j ^ 2]);
    const bool lb = (p & 2) != 0;
    #pragma unroll
    for (int j = 0; j < 8; ++j) v[j] = (lb == ((j & 2) != 0)) ? v[j] : t[j];
  }
  { float t[8];
    #pragma unroll
    for (int j = 0; j < 8; ++j) t[j] = dpp_xor4(v[j ^ 4]);
    const bool lb = (p & 4) != 0;
    #pragma unroll
    for (int j = 0; j < 8; ++j) v[j] = (lb == ((j & 4) != 0)) ? v[j] : t[j];
  }
}

// forward 8-pt DCT (y = D x), butterflied
__device__ __forceinline__ void fdct8b(float x[8]) {
  const float s0 = x[0] + x[7], s1 = x[1] + x[6], s2 = x[2] + x[5], s3 = x[3] + x[4];
  const float d0 = x[0] - x[7], d1 = x[1] - x[6], d2 = x[2] - x[5], d3 = x[3] - x[4];
  const float t0 = s0 + s3, t1 = s1 + s2, t2 = s0 - s3, t3 = s1 - s2;
  x[0] = CA * (t0 + t1);
  x[4] = CA * (t0 - t1);
  x[2] = fmaf(CC0, t2,  CC1 * t3);
  x[6] = fmaf(CC1, t2, -CC0 * t3);
  x[1] = fmaf(CB0, d0, fmaf( CB1, d1, fmaf( CB2, d2,  CB3 * d3)));
  x[3] = fmaf(CB1, d0, fmaf(-CB3, d1, fmaf(-CB0, d2, -CB2 * d3)));
  x[5] = fmaf(CB2, d0, fmaf(-CB0, d1, fmaf( CB3, d2,  CB1 * d3)));
  x[7] = fmaf(CB3, d0, fmaf(-CB2, d1, fmaf( CB1, d2, -CB0 * d3)));
}
// inverse 8-pt DCT (o = D^T y), butterflied
__device__ __forceinline__ void idct8b(float y[8]) {
  const float pe = CA * (y[0] + y[4]), qe = CA * (y[0] - y[4]);
  const float re = fmaf(CC0, y[2],  CC1 * y[6]);
  const float se = fmaf(CC1, y[2], -CC0 * y[6]);
  const float E0 = pe + re, E3 = pe - re, E1 = qe + se, E2 = qe - se;
  const float O0 = fmaf(CB0, y[1], fmaf( CB1, y[3], fmaf( CB2, y[5],  CB3 * y[7])));
  const float O1 = fmaf(CB1, y[1], fmaf(-CB3, y[3], fmaf(-CB0, y[5], -CB2 * y[7])));
  const float O2 = fmaf(CB2, y[1], fmaf(-CB0, y[3], fmaf( CB3, y[5],  CB1 * y[7])));
  const float O3 = fmaf(CB3, y[1], fmaf(-CB2, y[3], fmaf( CB1, y[5], -CB0 * y[7])));
  y[0] = E0 + O0; y[7] = E0 - O0;
  y[1] = E1 + O1; y[6] = E1 - O1;
  y[2] = E2 + O2; y[5] = E2 - O2;
  y[3] = E3 + O3; y[4] = E3 - O3;
}

// f64 recompute of dequantized coefficient (i,j). mode 0 = Y (base = 8x8
// block base), mode 1 = Cb, mode 2 = Cr (base = 16x16 tile base). Cold.
__device__ __attribute__((noinline)) float rescue_coef(
    const float* __restrict__ quant, const float* __restrict__ base,
    int mode, int i, int j)
{
  double acc = 0.0;
  if (mode == 0) {
    #pragma unroll 1
    for (int k = 0; k < 8; ++k) {
      double e = 0.0;
      #pragma unroll
      for (int l = 0; l < 8; ++l) {
        const size_t off = (size_t)k * 512 + l;
        const double rr = (double)base[off];
        const double gg = (double)base[262144 + off];
        const double bb = (double)base[524288 + off];
        double y = 0.299 * rr + 0.587 * gg + 0.114 * bb;
        y = fmin(fmax(y, 0.0), 1.0) - LEVELD;
        e += y * DMATD[j * 8 + l];
      }
      acc += DMATD[i * 8 + k] * e;
    }
  } else {
    const double c0 = (mode == 1) ? -0.168735892 : 0.5;
    const double c1 = (mode == 1) ? -0.331264108 : -0.418687589;
    const double c2 = (mode == 1) ?  0.5         : -0.081312411;
    #pragma unroll 1
    for (int k = 0; k < 8; ++k) {
      double e = 0.0;
      #pragma unroll 1
      for (int l = 0; l < 8; ++l) {
        double m = 0.0;
        #pragma unroll
        for (int dr = 0; dr < 2; ++dr)
          #pragma unroll
          for (int dc = 0; dc < 2; ++dc) {
            const size_t off = (size_t)(2 * k + dr) * 512 + (2 * l + dc);
            const double rr = (double)base[off];
            const double gg = (double)base[262144 + off];
            const double bb = (double)base[524288 + off];
            const double v = c0 * rr + c1 * gg + c2 * bb;
            m += fmin(fmax(v + LEVELD, 0.0), 1.0) - LEVELD;
          }
        e += (0.25 * m) * DMATD[j * 8 + l];
      }
      acc += DMATD[i * 8 + k] * e;
    }
  }
  const double qd = rint((double)quant[i * 8 + j] * 255.0) * (1.0 / 255.0);
  return (float)(rint(acc / qd) * qd);
}

// per-block codec: DCT -> quant(round; deferred f64 rescue) -> IDCT, in place
__device__ __forceinline__ void codec8(float x[8], const float qv[8], const float rq[8],
                                       int p, int mode, const float* __restrict__ base,
                                       const float* __restrict__ quant)
{
  fdct8b(x); transpose8(x, p); fdct8b(x);
  unsigned bad = 0u;
  #pragma unroll
  for (int i = 0; i < 8; ++i) {
    const float tt = x[i] * rq[i];
    const float rt = rintf(tt);
    if (fabsf(tt - rt) > 0.5f - BAND) bad |= (1u << i);
    x[i] = rt * qv[i];
  }
  if (__builtin_expect(bad != 0u, 0)) {     // cold, branched-over patch
    do {
      const int i = __builtin_ctz(bad);
      bad &= bad - 1u;
      const float fix = rescue_coef(quant, base, mode, i, p);
      #pragma unroll
      for (int k = 0; k < 8; ++k) x[k] = (k == i) ? fix : x[k];
    } while (bad != 0u);
  }
  idct8b(x); transpose8(x, p); idct8b(x);
}

// color + chroma-mean staging for one Y round (loads already in registers)
__device__ __forceinline__ void color_stage(
    const float4 L6[6], int tY, int qr, int qc, int p,
    float4* __restrict__ CHW, float rout[8])
{
  const float RL[8] = {L6[0].x, L6[0].y, L6[0].z, L6[0].w, L6[1].x, L6[1].y, L6[1].z, L6[1].w};
  const float GL[8] = {L6[2].x, L6[2].y, L6[2].z, L6[2].w, L6[3].x, L6[3].y, L6[3].z, L6[3].w};
  const float BL[8] = {L6[4].x, L6[4].y, L6[4].z, L6[4].w, L6[5].x, L6[5].y, L6[5].z, L6[5].w};

  float cbv[8], crv[8];
  #pragma unroll
  for (int l = 0; l < 8; ++l) {
    const float rr = RL[l], gg = GL[l], bb = BL[l];
    const float y  = fmaf(0.114f, bb, fmaf(0.587f, gg, 0.299f * rr));
    const float cb = fmaf(0.5f, bb, fmaf(-0.331264108f, gg, -0.168735892f * rr));
    const float cr = fmaf(-0.081312411f, bb, fmaf(-0.418687589f, gg, 0.5f * rr));
    rout[l] = fminf(fmaxf(y,           0.0f), 1.0f) - LEVELF;
    cbv[l]  = fminf(fmaxf(cb + LEVELF, 0.0f), 1.0f) - LEVELF;
    crv[l]  = fminf(fmaxf(cr + LEVELF, 0.0f), 1.0f) - LEVELF;
  }
  float ch[4];
  #pragma unroll
  for (int j = 0; j < 4; ++j) {
    const float cbh = cbv[2 * j] + cbv[2 * j + 1];
    const float crh = crv[2 * j] + crv[2 * j + 1];
    const float cbs = cbh + dpp_xor1(cbh);
    const float crs = crh + dpp_xor1(crh);
    ch[j] = 0.25f * ((p & 1) ? crs : cbs);   // even lanes: cb, odd: cr
  }
  const int crow = qr * 4 + (p >> 1);
  const int slot = ((((p & 1) * 4 + tY) * 16) + crow * 2 + qc) ^ ((tY << 1) | qr);
  CHW[slot] = make_float4(ch[0], ch[1], ch[2], ch[3]);
}

// upsample chroma from LDS, YCC->RGB, clamp, nontemporal store one Y round
__device__ __forceinline__ void out_phase(
    float* __restrict__ ob, int tY, int qr, int qc, int p,
    const float4* __restrict__ CHW, const float r[8])
{
  const int crow = qr * 4 + (p >> 1);
  const int swz = (tY << 1) | qr;
  const float4 cb4 = CHW[((tY * 16) + crow * 2 + qc) ^ swz];
  const float4 cr4 = CHW[(((4 + tY) * 16) + crow * 2 + qc) ^ swz];
  const float cba[4] = {cb4.x, cb4.y, cb4.z, cb4.w};
  const float cra[4] = {cr4.x, cr4.y, cr4.z, cr4.w};

  float RR[8], GG[8], BB[8];
  #pragma unroll
  for (int l = 0; l < 8; ++l) {
    const float y2 = r[l] + LEVELF;          // chroma LEVEL offsets cancel
    const float cbb = cba[l >> 1], crr = cra[l >> 1];
    float ro = fmaf(1.402f, crr, y2);
    float go = y2 - 0.344136286f * cbb - 0.714136286f * crr;
    float bo = fmaf(1.772f, cbb, y2);
    RR[l] = fminf(fmaxf(ro, 0.0f), 1.0f);
    GG[l] = fminf(fmaxf(go, 0.0f), 1.0f);
    BB[l] = fminf(fmaxf(bo, 0.0f), 1.0f);
  }
  float* op = ob + (size_t)(qr * 8 + p) * 512 + tY * 16 + qc * 8;
  nt_store4(op,              RR[0], RR[1], RR[2], RR[3]);
  nt_store4(op + 4,          RR[4], RR[5], RR[6], RR[7]);
  nt_store4(op + 262144,     GG[0], GG[1], GG[2], GG[3]);
  nt_store4(op + 262148,     GG[4], GG[5], GG[6], GG[7]);
  nt_store4(op + 524288,     BB[0], BB[1], BB[2], BB[3]);
  nt_store4(op + 524292,     BB[4], BB[5], BB[6], BB[7]);
}

__global__ __launch_bounds__(64, 4) void jpeg_fused(
    const float* __restrict__ in, const float* __restrict__ quant,
    float* __restrict__ out)
{
  __shared__ float4 CH[128];   // 8 chroma blocks (swizzled slots), 2 KiB

  const int lane = threadIdx.x;
  const int g = lane >> 3, p = lane & 7;
  const int tx = g >> 2, qr = (g >> 1) & 1, qc = g & 1;

  const int u    = blockIdx.x;                // unit = 4 tiles in a row
  const int img  = u >> 8;
  const int trow = (u >> 3) & 31;
  const int tcq  = u & 7;
  const size_t tboff = (size_t)img * 786432 + (size_t)trow * 16 * 512 + (size_t)tcq * 64;
  const float* tb = in + tboff;
  float* ob = out + tboff;

  // ---- hoisted global loads: both Y rounds' pixels + quant column ----
  float4 L[2][6];
  #pragma unroll
  for (int h = 0; h < 2; ++h) {
    const int tY = 2 * h + tx;
    const float* pb = tb + (size_t)(qr * 8 + p) * 512 + tY * 16 + qc * 8;
    L[h][0] = *(const float4*)(pb);
    L[h][1] = *(const float4*)(pb + 4);
    L[h][2] = *(const float4*)(pb + 262144);
    L[h][3] = *(const float4*)(pb + 262148);
    L[h][4] = *(const float4*)(pb + 524288);
    L[h][5] = *(const float4*)(pb + 524292);
  }
  float qf[8];
  #pragma unroll
  for (int i = 0; i < 8; ++i) qf[i] = quant[i * 8 + p];

  // quantizer column p in f32: rintf(q*255) is exact (q*255 in [40,50]);
  // <=1-ulp dequant difference vs f64, arbitrated by the f64 rescue anyway
  float qv[8], rq[8];
  #pragma unroll
  for (int i = 0; i < 8; ++i) {
    qv[i] = rintf(qf[i] * 255.0f) * (1.0f / 255.0f);
    rq[i] = 1.0f / qv[i];
  }

  // ---- color + chroma staging for both rounds ----
  float rA[8], rB[8];
  color_stage(L[0], 2 * 0 + tx, qr, qc, p, CH, rA);
  color_stage(L[1], 2 * 1 + tx, qr, qc, p, CH, rB);
  __builtin_amdgcn_wave_barrier();

  // ---- Y codecs (call-free fast path) ----
  const float* blkA = tb + (size_t)(qr * 8) * 512 + (2 * 0 + tx) * 16 + qc * 8;
  const float* blkB = tb + (size_t)(qr * 8) * 512 + (2 * 1 + tx) * 16 + qc * 8;
  codec8(rA, qv, rq, p, 0, blkA, quant);
  codec8(rB, qv, rq, p, 0, blkB, quant);

  // ---- chroma codec round: 8 blocks (g>>2: 0=Cb,1=Cr; g&3: unit tile) ----
  {
    const int cpar = g >> 2, ct = g & 3;
    const int pre  = (cpar * 4 + ct) * 16 + p * 2;
    const int swz  = (ct << 1) | (p >> 2);
    const int sl = pre ^ swz, sh = (pre + 1) ^ swz;
    const float4 a = CH[sl];
    const float4 b = CH[sh];
    float xc[8] = {a.x, a.y, a.z, a.w, b.x, b.y, b.z, b.w};
    codec8(xc, qv, rq, p, 1 + cpar, tb + ct * 16, quant);
    CH[sl] = make_float4(xc[0], xc[1], xc[2], xc[3]);
    CH[sh] = make_float4(xc[4], xc[5], xc[6], xc[7]);
  }
  __builtin_amdgcn_wave_barrier();

  // ---- output both rounds (non-temporal stores) ----
  out_phase(ob, 2 * 0 + tx, qr, qc, p, CH, rA);
  out_phase(ob, 2 * 1 + tx, qr, qc, p, CH, rB);
}

extern "C" void kernel_launch(void* const* d_in, const int* in_sizes, int n_in,
                              void* d_out, int out_size, void* d_ws, size_t ws_size,
                              hipStream_t stream) {
  const float* in    = (const float*)d_in[0];
  const float* quant = (const float*)d_in[1];  // only quantize[0] (64 floats) used
  float* out = (float*)d_out;

  // 8192 single-wave workgroups (32 img x 32 trow x 8 four-tile units)
  jpeg_fused<<<dim3(8192), dim3(64), 0, stream>>>(in, quant, out);
}